// Round 6
// baseline (2879.190 us; speedup 1.0000x reference)
//
#include <hip/hip_runtime.h>
#include <hip/hip_bf16.h>

// Problem constants (match reference)
#define NN 100000
#define EE 1600000
#define CC 8
#define HH 64
#define NF 140
#define CF 18
#define BB 16
#define NROWS (NN * CC)          // 800000 rows of [64]
#define ALPHA 0.2f

// X layout: interleaved [n][c][64] (row = n*8+c). R4's slice-major regressed.
// R6: non-temporal hints on all pure streams so X (the gather target, 102 MB)
// stays L3-resident; fused-kernel grid 1024->4096 (R5 occupancy was 26%,
// launch-capped at 4 blocks/CU).

typedef unsigned short u16;
typedef unsigned int u32;
typedef __attribute__((ext_vector_type(8))) short short8;   // 8 bf16 (4 VGPRs)
typedef __attribute__((ext_vector_type(4))) float f32x4;    // MFMA accum
typedef __attribute__((ext_vector_type(4))) unsigned int u32x4;
typedef __attribute__((ext_vector_type(4))) float fv4;

__device__ __forceinline__ float rdlane(float v, int l) {
    return __int_as_float(__builtin_amdgcn_readlane(__float_as_int(v), l));
}
__device__ __forceinline__ float lrelu(float x) { return x > 0.f ? x : ALPHA * x; }
__device__ __forceinline__ float wave_sum64(float v) {
#pragma unroll
    for (int m = 1; m < 64; m <<= 1) v += __shfl_xor(v, m, 64);
    return v;
}
__device__ __forceinline__ int lower_bound_g(const int* a, int n, int key) {
    int lo = 0, hi = n;
    while (lo < hi) { int mid = (lo + hi) >> 1; if (a[mid] < key) lo = mid + 1; else hi = mid; }
    return lo;
}
__device__ __forceinline__ float b2f(u16 u) { return __uint_as_float(((u32)u) << 16); }
__device__ __forceinline__ u32 f2b(float f) {
    u32 u = __float_as_uint(f);
    return (u + 0x7fffu + ((u >> 16) & 1u)) >> 16;
}
__device__ __forceinline__ u32 pack2(float lo, float hi) {
    return f2b(lo) | (f2b(hi) << 16);
}
__device__ __forceinline__ short8 ld_frag(const u16* p) {
    union { uint4 u; short8 s; } c;
    c.u = *(const uint4*)p;
    return c.s;
}
__device__ __forceinline__ void acc8(float* a, uint4 t) {
    a[0] += __uint_as_float(t.x << 16); a[1] += __uint_as_float(t.x & 0xffff0000u);
    a[2] += __uint_as_float(t.y << 16); a[3] += __uint_as_float(t.y & 0xffff0000u);
    a[4] += __uint_as_float(t.z << 16); a[5] += __uint_as_float(t.z & 0xffff0000u);
    a[6] += __uint_as_float(t.w << 16); a[7] += __uint_as_float(t.w & 0xffff0000u);
}

// ---------------- CSR build ----------------
__global__ __launch_bounds__(256) void deg_count_k(const int* __restrict__ src,
                                                   const int* __restrict__ dst,
                                                   int* __restrict__ deg) {
    int e = blockIdx.x * 256 + threadIdx.x;
    if (e < EE) atomicAdd(&deg[dst[e]], 1);
    else if (e < 2 * EE) atomicAdd(&deg[src[e - EE]], 1);
}

__global__ __launch_bounds__(1024) void scan1_k(const int* __restrict__ deg,
                                                int* __restrict__ row_ptr,
                                                int* __restrict__ bsum, int n) {
    __shared__ int lds[17];
    int i = blockIdx.x * 1024 + threadIdx.x;
    int lane = threadIdx.x & 63, wv = threadIdx.x >> 6;
    int val = (i < n) ? deg[i] : 0;
    int v = val;
#pragma unroll
    for (int d = 1; d < 64; d <<= 1) {
        int t = __shfl_up(v, d, 64);
        if (lane >= d) v += t;
    }
    if (lane == 63) lds[wv] = v;
    __syncthreads();
    if (threadIdx.x == 0) {
        int run = 0;
#pragma unroll
        for (int k = 0; k < 16; k++) { int t = lds[k]; lds[k] = run; run += t; }
        lds[16] = run;
    }
    __syncthreads();
    if (i < n) row_ptr[i] = v - val + lds[wv];
    if (threadIdx.x == 1023) bsum[blockIdx.x] = lds[16];
}

__global__ void scan2_k(int* __restrict__ bsum, int nb) {
    int run = 0;
    for (int b = 0; b < nb; b++) { int t = bsum[b]; bsum[b] = run; run += t; }
    bsum[nb] = run;
}

__global__ __launch_bounds__(1024) void scan3_k(int* __restrict__ row_ptr,
                                                int* __restrict__ cursor,
                                                const int* __restrict__ bsum,
                                                int n, int nb) {
    int i = blockIdx.x * 1024 + threadIdx.x;
    if (i < n) {
        int v = row_ptr[i] + bsum[blockIdx.x];
        row_ptr[i] = v;
        cursor[i] = v;
    }
    if (i == 0) row_ptr[n] = bsum[nb];
}

__global__ __launch_bounds__(256) void place_k(const int* __restrict__ src,
                                               const int* __restrict__ dst,
                                               int* __restrict__ cursor,
                                               int* __restrict__ col) {
    int e = blockIdx.x * 256 + threadIdx.x;
    int node, other;
    if (e < EE) { node = dst[e]; other = src[e]; }
    else if (e < 2 * EE) { node = src[e - EE]; other = dst[e - EE]; }
    else return;
    int pos = atomicAdd(&cursor[node], 1);
    col[pos] = other;
}

// ---------------- weight prep: transposed bf16 weights ----------------
__global__ __launch_bounds__(256) void prep_w_k(const float* __restrict__ Wd1, const float* __restrict__ Wp1,
                                                const float* __restrict__ Wd2, const float* __restrict__ Wp2,
                                                const float* __restrict__ Wd0nf, const float* __restrict__ Wp0nf,
                                                u16* __restrict__ WT) {
    int i = blockIdx.x * 256 + threadIdx.x;
    if (i < 4 * 4096) {
        int w = i >> 12, idx = i & 4095;
        int n = idx >> 6, k = idx & 63;
        const float* W = (w == 0) ? Wd1 : (w == 1) ? Wp1 : (w == 2) ? Wd2 : Wp2;
        WT[w * 4096 + n * 64 + k] = (u16)f2b(W[k * 64 + n]);
    } else {
        int j = i - 4 * 4096;
        if (j < 2 * 64 * 160) {
            int w = j / 10240, idx = j % 10240;
            int n = idx / 160, k = idx % 160;
            const float* W = w ? Wp0nf : Wd0nf;
            WT[16384 + w * 10240 + n * 160 + k] = (k < 140) ? (u16)f2b(W[k * 64 + n]) : (u16)0;
        }
    }
}

// op_d/op_p tables: [120][64] f32 = op_emb @ W_top (rows 0..63 of W_d0 / W_p0)
__global__ __launch_bounds__(256) void op_dp_k(const float* __restrict__ op_emb,
                                               const float* __restrict__ Wd_top,
                                               const float* __restrict__ Wp_top,
                                               float* __restrict__ op_d,
                                               float* __restrict__ op_p) {
    int lane = threadIdx.x & 63;
    int wid = (blockIdx.x * 256 + threadIdx.x) >> 6;
    if (wid >= 120) return;
    float v = op_emb[wid * 64 + lane];
    float ad = 0.f, ap = 0.f;
    for (int k = 0; k < 64; k++) {
        float s = rdlane(v, k);
        ad = fmaf(s, Wd_top[k * 64 + lane], ad);
        ap = fmaf(s, Wp_top[k * 64 + lane], ap);
    }
    op_d[wid * 64 + lane] = ad;
    op_p[wid * 64 + lane] = ap;
}

// ---------------- nf projections via MFMA ----------------
__global__ __launch_bounds__(256) void nf_mfma_k(const float* __restrict__ nf,
                                                 const u16* __restrict__ WdT0,
                                                 const u16* __restrict__ WpT0,
                                                 u16* __restrict__ nf_d,
                                                 u16* __restrict__ nf_p) {
    int lane = threadIdx.x & 63;
    int m = lane & 15, q = lane >> 4;
    int wid = (blockIdx.x * 256 + threadIdx.x) >> 6;
    int nw = (gridDim.x * 256) >> 6;
    for (int rb = wid; rb < NN / 16; rb += nw) {
        int node0 = rb * 16;
        const float* row = nf + (size_t)(node0 + m) * 140;
        short8 af[5];
#pragma unroll
        for (int s = 0; s < 5; s++) {
            int k0 = s * 32 + q * 8;
            float f[8];
            if (s < 4) {
                fv4 lo = __builtin_nontemporal_load((const fv4*)(row + k0));
                fv4 hi = __builtin_nontemporal_load((const fv4*)(row + k0 + 4));
                f[0]=lo.x; f[1]=lo.y; f[2]=lo.z; f[3]=lo.w;
                f[4]=hi.x; f[5]=hi.y; f[6]=hi.z; f[7]=hi.w;
            } else {
#pragma unroll
                for (int j = 0; j < 8; j++) f[j] = 0.f;
                if (q == 0) {
                    fv4 lo = __builtin_nontemporal_load((const fv4*)(row + 128));
                    fv4 hi = __builtin_nontemporal_load((const fv4*)(row + 132));
                    f[0]=lo.x; f[1]=lo.y; f[2]=lo.z; f[3]=lo.w;
                    f[4]=hi.x; f[5]=hi.y; f[6]=hi.z; f[7]=hi.w;
                } else if (q == 1) {
                    fv4 lo = __builtin_nontemporal_load((const fv4*)(row + 136));
                    f[0]=lo.x; f[1]=lo.y; f[2]=lo.z; f[3]=lo.w;
                }
            }
            short8 t;
#pragma unroll
            for (int j = 0; j < 8; j++) t[j] = (short)f2b(f[j]);
            af[s] = t;
        }
        f32x4 ad[4], ap[4];
#pragma unroll
        for (int t = 0; t < 4; t++) {
            ad[t] = (f32x4){0.f, 0.f, 0.f, 0.f};
            ap[t] = (f32x4){0.f, 0.f, 0.f, 0.f};
        }
#pragma unroll
        for (int s = 0; s < 5; s++) {
#pragma unroll
            for (int t = 0; t < 4; t++) {
                int boff = (t * 16 + m) * 160 + s * 32 + q * 8;
                short8 bdw = ld_frag(WdT0 + boff);
                short8 bpw = ld_frag(WpT0 + boff);
                ad[t] = __builtin_amdgcn_mfma_f32_16x16x32_bf16(af[s], bdw, ad[t], 0, 0, 0);
                ap[t] = __builtin_amdgcn_mfma_f32_16x16x32_bf16(af[s], bpw, ap[t], 0, 0, 0);
            }
        }
#pragma unroll
        for (int r = 0; r < 4; r++) {
            size_t nrow = (size_t)(node0 + q * 4 + r);
#pragma unroll
            for (int t = 0; t < 4; t++) {
                nf_d[nrow * 64 + t * 16 + m] = (u16)f2b(ad[t][r]);
                nf_p[nrow * 64 + t * 16 + m] = (u16)f2b(ap[t][r]);
            }
        }
    }
}

// X[row=(n,c)][l] (bf16) = op_d[op[n]][l] + nf_d[n][l] + cf[n,c,:] @ Wbot
__global__ __launch_bounds__(256) void hd0_asm_k(u16* __restrict__ X,
                                                 const float* __restrict__ cf,
                                                 const int* __restrict__ op_ids,
                                                 const u16* __restrict__ nf_d,
                                                 const float* __restrict__ op_d,
                                                 const float* __restrict__ Wbot) {
    int lane = threadIdx.x & 63;
    float wb[18];
#pragma unroll
    for (int k = 0; k < 18; k++) wb[k] = Wbot[k * 64 + lane];
    int wid = (blockIdx.x * 256 + threadIdx.x) >> 6;
    int nw = (gridDim.x * 256) >> 6;
    for (int row = wid; row < NROWS; row += nw) {
        int n = row >> 3;
        float cfv = (lane < 18) ? __builtin_nontemporal_load(cf + (size_t)row * 18 + lane) : 0.f;
        float acc = op_d[op_ids[n] * 64 + lane] + b2f(nf_d[(size_t)n * 64 + lane]);
#pragma unroll
        for (int k = 0; k < 18; k++) acc = fmaf(rdlane(cfv, k), wb[k], acc);
        __builtin_nontemporal_store((u16)f2b(acc), X + (size_t)row * 64 + lane);
    }
}

// ---------------- SpMM layer 0 (unfused), unroll-4, nt store ----------------
__global__ __launch_bounds__(256) void spmm_k(const uint4* __restrict__ X4,
                                              uint4* __restrict__ Y4,
                                              const int* __restrict__ row_ptr,
                                              const int* __restrict__ col) {
    int wid = (blockIdx.x * 256 + threadIdx.x) >> 6;
    int lane = threadIdx.x & 63;
    if (wid >= NN) return;
    int start = row_ptr[wid];
    int end = row_ptr[wid + 1];
    float a[8] = {0.f, 0.f, 0.f, 0.f, 0.f, 0.f, 0.f, 0.f};
    int j = start;
    for (; j + 4 <= end; j += 4) {
        int s0 = col[j], s1 = col[j + 1], s2 = col[j + 2], s3 = col[j + 3];
        uint4 t0 = X4[(size_t)s0 * 64 + lane];
        uint4 t1 = X4[(size_t)s1 * 64 + lane];
        uint4 t2 = X4[(size_t)s2 * 64 + lane];
        uint4 t3 = X4[(size_t)s3 * 64 + lane];
        acc8(a, t0); acc8(a, t1); acc8(a, t2); acc8(a, t3);
    }
    for (; j < end; j++) {
        uint4 t0 = X4[(size_t)col[j] * 64 + lane];
        acc8(a, t0);
    }
    u32x4 o;
    o.x = pack2(a[0], a[1]);
    o.y = pack2(a[2], a[3]);
    o.z = pack2(a[4], a[5]);
    o.w = pack2(a[6], a[7]);
    __builtin_nontemporal_store(o, (u32x4*)Y4 + (size_t)wid * 64 + lane);
}

// ---------------- combine layer 0 ----------------
__global__ __launch_bounds__(256) void combine0_k(u16* __restrict__ X,
                                                  const u16* __restrict__ Y,
                                                  const float* __restrict__ cf,
                                                  const int* __restrict__ op_ids,
                                                  const u16* __restrict__ nf_p,
                                                  const float* __restrict__ op_p,
                                                  const float* __restrict__ WpBot,
                                                  const float* __restrict__ bd,
                                                  const float* __restrict__ bp) {
    int lane = threadIdx.x & 63;
    float wb[18];
#pragma unroll
    for (int k = 0; k < 18; k++) wb[k] = WpBot[k * 64 + lane];
    float bdl = bd[lane], bpl = bp[lane];
    int wid = (blockIdx.x * 256 + threadIdx.x) >> 6;
    int nw = (gridDim.x * 256) >> 6;
    for (int row = wid; row < NROWS; row += nw) {
        int n = row >> 3;
        float yv = b2f(__builtin_nontemporal_load(Y + (size_t)row * 64 + lane));
        float cfv = (lane < 18) ? __builtin_nontemporal_load(cf + (size_t)row * 18 + lane) : 0.f;
        float accp = op_p[op_ids[n] * 64 + lane] + b2f(nf_p[(size_t)n * 64 + lane]);
#pragma unroll
        for (int k = 0; k < 18; k++) accp = fmaf(rdlane(cfv, k), wb[k], accp);
        float t = accp + bpl + lrelu(yv + bdl);
        float sq = wave_sum64(t * t);
        __builtin_nontemporal_store((u16)f2b(t * rsqrtf(fmaxf(sq, 1e-12f))),
                                    X + (size_t)row * 64 + lane);
    }
}

// ---------------- FUSED SpMM + combine (layers 1/2) ----------------
// One wave per 2 nodes (16 rows). Gather into f32 regs, LDS transpose
// (stride 72 u16), 16 MFMAs, fused epilogue, nt store to Xout.
__global__ __launch_bounds__(256) void fused_spmm_combine_k(const u16* __restrict__ Xin,
                                                            u16* __restrict__ Xout,
                                                            const int* __restrict__ row_ptr,
                                                            const int* __restrict__ col,
                                                            const u16* __restrict__ WdT,
                                                            const u16* __restrict__ WpT,
                                                            const float* __restrict__ bd,
                                                            const float* __restrict__ bp) {
    __shared__ u16 lds_t[4 * 16 * 72];
    int lane = threadIdx.x & 63;
    u16* L = lds_t + (threadIdx.x >> 6) * (16 * 72);
    int m = lane & 15, q = lane >> 4;
    const uint4* X4 = (const uint4*)Xin;
    short8 bdf[4][2], bpf[4][2];
#pragma unroll
    for (int t = 0; t < 4; t++)
#pragma unroll
        for (int s = 0; s < 2; s++) {
            int off = (t * 16 + m) * 64 + s * 32 + q * 8;
            bdf[t][s] = ld_frag(WdT + off);
            bpf[t][s] = ld_frag(WpT + off);
        }
    float bdv[4], bpv[4];
#pragma unroll
    for (int t = 0; t < 4; t++) { bdv[t] = bd[t * 16 + m]; bpv[t] = bp[t * 16 + m]; }

    int wid = (blockIdx.x * 256 + threadIdx.x) >> 6;
    int nw = (gridDim.x * 256) >> 6;
    for (int pb = wid; pb < NN / 2; pb += nw) {
#pragma unroll
        for (int p = 0; p < 2; p++) {
            int node = pb * 2 + p;
            int start = row_ptr[node], end = row_ptr[node + 1];
            float a[8] = {0.f, 0.f, 0.f, 0.f, 0.f, 0.f, 0.f, 0.f};
            int j = start;
            for (; j + 4 <= end; j += 4) {
                int s0 = col[j], s1 = col[j + 1], s2 = col[j + 2], s3 = col[j + 3];
                uint4 t0 = X4[(size_t)s0 * 64 + lane];
                uint4 t1 = X4[(size_t)s1 * 64 + lane];
                uint4 t2 = X4[(size_t)s2 * 64 + lane];
                uint4 t3 = X4[(size_t)s3 * 64 + lane];
                acc8(a, t0); acc8(a, t1); acc8(a, t2); acc8(a, t3);
            }
            for (; j < end; j++) {
                uint4 t0 = X4[(size_t)col[j] * 64 + lane];
                acc8(a, t0);
            }
            uint4 o;
            o.x = pack2(a[0], a[1]);
            o.y = pack2(a[2], a[3]);
            o.z = pack2(a[4], a[5]);
            o.w = pack2(a[6], a[7]);
            *(uint4*)(L + (size_t)(p * 8 + (lane >> 3)) * 72 + (lane & 7) * 8) = o;
        }
        short8 ay0 = ld_frag(L + m * 72 + q * 8);
        short8 ay1 = ld_frag(L + m * 72 + 32 + q * 8);
        const u16* xr = Xin + ((size_t)(pb * 16 + m)) * 64 + q * 8;
        short8 ax0 = ld_frag(xr), ax1 = ld_frag(xr + 32);
        f32x4 ad[4], ap[4];
#pragma unroll
        for (int t = 0; t < 4; t++) {
            ad[t] = (f32x4){0.f, 0.f, 0.f, 0.f};
            ap[t] = (f32x4){0.f, 0.f, 0.f, 0.f};
        }
#pragma unroll
        for (int t = 0; t < 4; t++) {
            ad[t] = __builtin_amdgcn_mfma_f32_16x16x32_bf16(ay0, bdf[t][0], ad[t], 0, 0, 0);
            ad[t] = __builtin_amdgcn_mfma_f32_16x16x32_bf16(ay1, bdf[t][1], ad[t], 0, 0, 0);
            ap[t] = __builtin_amdgcn_mfma_f32_16x16x32_bf16(ax0, bpf[t][0], ap[t], 0, 0, 0);
            ap[t] = __builtin_amdgcn_mfma_f32_16x16x32_bf16(ax1, bpf[t][1], ap[t], 0, 0, 0);
        }
        float v[4][4], sq[4];
#pragma unroll
        for (int r = 0; r < 4; r++) sq[r] = 0.f;
#pragma unroll
        for (int t = 0; t < 4; t++)
#pragma unroll
            for (int r = 0; r < 4; r++) {
                float val = ap[t][r] + bpv[t] + lrelu(ad[t][r] + bdv[t]);
                v[t][r] = val;
                sq[r] += val * val;
            }
#pragma unroll
        for (int r = 0; r < 4; r++) {
#pragma unroll
            for (int mm = 1; mm < 16; mm <<= 1) sq[r] += __shfl_xor(sq[r], mm, 64);
            float sc = rsqrtf(fmaxf(sq[r], 1e-12f));
            u16* orow = Xout + ((size_t)(pb * 16 + q * 4 + r)) * 64 + m;
#pragma unroll
            for (int t = 0; t < 4; t++)
                __builtin_nontemporal_store((u16)f2b(v[t][r] * sc), orow + t * 16);
        }
    }
}

// ---------------- pooling ----------------
__global__ __launch_bounds__(256) void pool_k(const u16* __restrict__ X,
                                              const int* __restrict__ graph_ids,
                                              float* __restrict__ pooled) {
    int g = blockIdx.x >> 3, c = blockIdx.x & 7;
    int lane = threadIdx.x & 63, w = threadIdx.x >> 6;
    int start = lower_bound_g(graph_ids, NN, g);
    int end = lower_bound_g(graph_ids, NN, g + 1);
    float acc = 0.f;
    for (int n = start + w; n < end; n += 4)
        acc += b2f(X[((size_t)n * 8 + c) * 64 + lane]);
    __shared__ float lds[4][64];
    lds[w][lane] = acc;
    __syncthreads();
    if (w == 0) {
        float s = lds[0][lane] + lds[1][lane] + lds[2][lane] + lds[3][lane];
        pooled[(size_t)(g * 8 + c) * 64 + lane] = s;
    }
}

// ---------------- final MLP over 128 (b,c) rows ----------------
__global__ __launch_bounds__(256) void mlp_k(const float* __restrict__ pooled,
                                             const float* __restrict__ W0, const float* __restrict__ b0,
                                             const float* __restrict__ W1, const float* __restrict__ b1,
                                             const float* __restrict__ W2, const float* __restrict__ b2,
                                             float* __restrict__ out) {
    int lane = threadIdx.x & 63;
    int row = blockIdx.x * 4 + (threadIdx.x >> 6);
    if (row >= BB * CC) return;
    float b0l = b0[lane], b1l = b1[lane], w2l = W2[lane], b2s = b2[0];
    float p = pooled[(size_t)row * 64 + lane];
    float a = 0.f;
    for (int k = 0; k < 64; k++) a = fmaf(rdlane(p, k), W0[k * 64 + lane], a);
    float h0 = lrelu(a + b0l);
    float a1 = 0.f;
    for (int k = 0; k < 64; k++) a1 = fmaf(rdlane(h0, k), W1[k * 64 + lane], a1);
    float h1 = lrelu(a1 + b1l);
    float v = wave_sum64(h1 * w2l);
    if (lane == 0) out[row] = v + b2s;
}

extern "C" void kernel_launch(void* const* d_in, const int* in_sizes, int n_in,
                              void* d_out, int out_size, void* d_ws, size_t ws_size,
                              hipStream_t stream) {
    const float* node_feats   = (const float*)d_in[0];
    const float* config_feats = (const float*)d_in[1];
    const int*   op_ids       = (const int*)d_in[2];
    const int*   src          = (const int*)d_in[3];
    const int*   dst          = (const int*)d_in[4];
    const int*   graph_ids    = (const int*)d_in[5];
    const float* op_emb       = (const float*)d_in[6];
    const float* W_d0 = (const float*)d_in[7],  *b_d0 = (const float*)d_in[8];
    const float* W_p0 = (const float*)d_in[9],  *b_p0 = (const float*)d_in[10];
    const float* W_d1 = (const float*)d_in[11], *b_d1 = (const float*)d_in[12];
    const float* W_p1 = (const float*)d_in[13], *b_p1 = (const float*)d_in[14];
    const float* W_d2 = (const float*)d_in[15], *b_d2 = (const float*)d_in[16];
    const float* W_p2 = (const float*)d_in[17], *b_p2 = (const float*)d_in[18];
    const float* W_m0 = (const float*)d_in[19], *b_m0 = (const float*)d_in[20];
    const float* W_m1 = (const float*)d_in[21], *b_m1 = (const float*)d_in[22];
    const float* W_m2 = (const float*)d_in[23], *b_m2 = (const float*)d_in[24];
    float* out = (float*)d_out;

    // workspace layout (~233 MiB). X/XB ping-pong; XB doubles as layer-0 Y.
    char* ws = (char*)d_ws;
    size_t off = 0;
    u16* X       = (u16*)(ws + off); off += (size_t)NROWS * 64 * 2;   // 102.4 MB
    u16* XB      = (u16*)(ws + off); off += (size_t)NROWS * 64 * 2;   // 102.4 MB
    u16* nf_d    = (u16*)(ws + off); off += (size_t)NN * 64 * 2;      // 12.8 MB
    u16* nf_p    = (u16*)(ws + off); off += (size_t)NN * 64 * 2;      // 12.8 MB
    float* op_d  = (float*)(ws + off); off += 120 * 64 * 4;
    float* op_p  = (float*)(ws + off); off += 120 * 64 * 4;
    int* row_ptr = (int*)(ws + off);   off += 400128;                 // N+1 padded
    int* cursor  = (int*)(ws + off);   off += 400128;
    int* deg     = (int*)(ws + off);   off += 400128;
    int* bsum    = (int*)(ws + off);   off += 512;                    // 98+1 padded
    int* col     = (int*)(ws + off);   off += (size_t)2 * EE * 4;     // 12.8 MB
    float* pooled = (float*)(ws + off); off += BB * CC * 64 * 4;
    u16* WT      = (u16*)(ws + off);   off += (4 * 4096 + 2 * 10240) * 2;
    (void)ws_size; (void)in_sizes; (void)n_in; (void)out_size;

    const int NB = (NN + 1023) / 1024;   // 98 scan blocks

    // ---- CSR build + weight prep ----
    hipMemsetAsync(deg, 0, (size_t)NN * 4, stream);
    deg_count_k<<<(2 * EE) / 256, 256, 0, stream>>>(src, dst, deg);
    prep_w_k<<<144, 256, 0, stream>>>(W_d1, W_p1, W_d2, W_p2,
                                      W_d0 + 64 * 64, W_p0 + 64 * 64, WT);
    scan1_k<<<NB, 1024, 0, stream>>>(deg, row_ptr, bsum, NN);
    scan2_k<<<1, 1, 0, stream>>>(bsum, NB);
    scan3_k<<<NB, 1024, 0, stream>>>(row_ptr, cursor, bsum, NN, NB);
    place_k<<<(2 * EE) / 256, 256, 0, stream>>>(src, dst, cursor, col);

    // ---- input projections ----
    op_dp_k<<<30, 256, 0, stream>>>(op_emb, W_d0, W_p0, op_d, op_p);
    nf_mfma_k<<<512, 256, 0, stream>>>(node_feats, WT + 16384, WT + 16384 + 10240, nf_d, nf_p);
    hd0_asm_k<<<2048, 256, 0, stream>>>(X, config_feats, op_ids, nf_d, op_d, W_d0 + 204 * 64);

    // ---- layer 0 (unfused: elementwise combine, no matmul needed) ----
    spmm_k<<<NN / 4, 256, 0, stream>>>((const uint4*)X, (uint4*)XB, row_ptr, col);
    combine0_k<<<2048, 256, 0, stream>>>(X, XB, config_feats, op_ids, nf_p, op_p,
                                         W_p0 + 204 * 64, b_d0, b_p0);
    // ---- layers 1,2: fused SpMM+combine, ping-pong X <-> XB ----
    fused_spmm_combine_k<<<4096, 256, 0, stream>>>(X, XB, row_ptr, col,
                                                   WT, WT + 4096, b_d1, b_p1);
    fused_spmm_combine_k<<<4096, 256, 0, stream>>>(XB, X, row_ptr, col,
                                                   WT + 8192, WT + 12288, b_d2, b_p2);

    // ---- pooling + MLP ----
    pool_k<<<BB * CC, 256, 0, stream>>>(X, graph_ids, pooled);
    mlp_k<<<32, 256, 0, stream>>>(pooled, W_m0, b_m0, W_m1, b_m1, W_m2, b_m2, out);
}

// Round 7
// 2286.754 us; speedup vs baseline: 1.2591x; 1.2591x over previous
//
#include <hip/hip_runtime.h>
#include <hip/hip_bf16.h>

// Problem constants (match reference)
#define NN 100000
#define EE 1600000
#define CC 8
#define HH 64
#define NF 140
#define CF 18
#define BB 16
#define NROWS (NN * CC)          // 800000 rows of [64]
#define ALPHA 0.2f

// X layout: interleaved [n][c][64] (row = n*8+c).
// nt policy (R7): nt ONLY on true one-way streams (node_feats, cf, layer-0 Y).
// X/XB stores are cached -- they are gather targets of the next kernel/pool.

typedef unsigned short u16;
typedef unsigned int u32;
typedef __attribute__((ext_vector_type(8))) short short8;   // 8 bf16 (4 VGPRs)
typedef __attribute__((ext_vector_type(4))) float f32x4;    // MFMA accum
typedef __attribute__((ext_vector_type(4))) unsigned int u32x4;
typedef __attribute__((ext_vector_type(4))) float fv4;

__device__ __forceinline__ float rdlane(float v, int l) {
    return __int_as_float(__builtin_amdgcn_readlane(__float_as_int(v), l));
}
__device__ __forceinline__ float lrelu(float x) { return x > 0.f ? x : ALPHA * x; }
__device__ __forceinline__ float wave_sum64(float v) {
#pragma unroll
    for (int m = 1; m < 64; m <<= 1) v += __shfl_xor(v, m, 64);
    return v;
}
__device__ __forceinline__ float b2f(u16 u) { return __uint_as_float(((u32)u) << 16); }
__device__ __forceinline__ u32 f2b(float f) {
    u32 u = __float_as_uint(f);
    return (u + 0x7fffu + ((u >> 16) & 1u)) >> 16;
}
__device__ __forceinline__ u32 pack2(float lo, float hi) {
    return f2b(lo) | (f2b(hi) << 16);
}
__device__ __forceinline__ short8 ld_frag(const u16* p) {
    union { uint4 u; short8 s; } c;
    c.u = *(const uint4*)p;
    return c.s;
}
__device__ __forceinline__ void acc8(float* a, uint4 t) {
    a[0] += __uint_as_float(t.x << 16); a[1] += __uint_as_float(t.x & 0xffff0000u);
    a[2] += __uint_as_float(t.y << 16); a[3] += __uint_as_float(t.y & 0xffff0000u);
    a[4] += __uint_as_float(t.z << 16); a[5] += __uint_as_float(t.z & 0xffff0000u);
    a[6] += __uint_as_float(t.w << 16); a[7] += __uint_as_float(t.w & 0xffff0000u);
}

// ---------------- CSR build ----------------
__global__ __launch_bounds__(256) void deg_count_k(const int* __restrict__ src,
                                                   const int* __restrict__ dst,
                                                   int* __restrict__ deg) {
    int e = blockIdx.x * 256 + threadIdx.x;
    if (e < EE) atomicAdd(&deg[dst[e]], 1);
    else if (e < 2 * EE) atomicAdd(&deg[src[e - EE]], 1);
}

__global__ __launch_bounds__(1024) void scan1_k(const int* __restrict__ deg,
                                                int* __restrict__ row_ptr,
                                                int* __restrict__ bsum, int n) {
    __shared__ int lds[17];
    int i = blockIdx.x * 1024 + threadIdx.x;
    int lane = threadIdx.x & 63, wv = threadIdx.x >> 6;
    int val = (i < n) ? deg[i] : 0;
    int v = val;
#pragma unroll
    for (int d = 1; d < 64; d <<= 1) {
        int t = __shfl_up(v, d, 64);
        if (lane >= d) v += t;
    }
    if (lane == 63) lds[wv] = v;
    __syncthreads();
    if (threadIdx.x == 0) {
        int run = 0;
#pragma unroll
        for (int k = 0; k < 16; k++) { int t = lds[k]; lds[k] = run; run += t; }
        lds[16] = run;
    }
    __syncthreads();
    if (i < n) row_ptr[i] = v - val + lds[wv];
    if (threadIdx.x == 1023) bsum[blockIdx.x] = lds[16];
}

__global__ void scan2_k(int* __restrict__ bsum, int nb) {
    int run = 0;
    for (int b = 0; b < nb; b++) { int t = bsum[b]; bsum[b] = run; run += t; }
    bsum[nb] = run;
}

__global__ __launch_bounds__(1024) void scan3_k(int* __restrict__ row_ptr,
                                                int* __restrict__ cursor,
                                                const int* __restrict__ bsum,
                                                int n, int nb) {
    int i = blockIdx.x * 1024 + threadIdx.x;
    if (i < n) {
        int v = row_ptr[i] + bsum[blockIdx.x];
        row_ptr[i] = v;
        cursor[i] = v;
    }
    if (i == 0) row_ptr[n] = bsum[nb];
}

__global__ __launch_bounds__(256) void place_k(const int* __restrict__ src,
                                               const int* __restrict__ dst,
                                               int* __restrict__ cursor,
                                               int* __restrict__ col) {
    int e = blockIdx.x * 256 + threadIdx.x;
    int node, other;
    if (e < EE) { node = dst[e]; other = src[e]; }
    else if (e < 2 * EE) { node = src[e - EE]; other = dst[e - EE]; }
    else return;
    int pos = atomicAdd(&cursor[node], 1);
    col[pos] = other;
}

// ---------------- weight prep: transposed bf16 weights ----------------
__global__ __launch_bounds__(256) void prep_w_k(const float* __restrict__ Wd1, const float* __restrict__ Wp1,
                                                const float* __restrict__ Wd2, const float* __restrict__ Wp2,
                                                const float* __restrict__ Wd0nf, const float* __restrict__ Wp0nf,
                                                u16* __restrict__ WT) {
    int i = blockIdx.x * 256 + threadIdx.x;
    if (i < 4 * 4096) {
        int w = i >> 12, idx = i & 4095;
        int n = idx >> 6, k = idx & 63;
        const float* W = (w == 0) ? Wd1 : (w == 1) ? Wp1 : (w == 2) ? Wd2 : Wp2;
        WT[w * 4096 + n * 64 + k] = (u16)f2b(W[k * 64 + n]);
    } else {
        int j = i - 4 * 4096;
        if (j < 2 * 64 * 160) {
            int w = j / 10240, idx = j % 10240;
            int n = idx / 160, k = idx % 160;
            const float* W = w ? Wp0nf : Wd0nf;
            WT[16384 + w * 10240 + n * 160 + k] = (k < 140) ? (u16)f2b(W[k * 64 + n]) : (u16)0;
        }
    }
}

// op_d/op_p tables: [120][64] f32 = op_emb @ W_top (rows 0..63 of W_d0 / W_p0)
__global__ __launch_bounds__(256) void op_dp_k(const float* __restrict__ op_emb,
                                               const float* __restrict__ Wd_top,
                                               const float* __restrict__ Wp_top,
                                               float* __restrict__ op_d,
                                               float* __restrict__ op_p) {
    int lane = threadIdx.x & 63;
    int wid = (blockIdx.x * 256 + threadIdx.x) >> 6;
    if (wid >= 120) return;
    float v = op_emb[wid * 64 + lane];
    float ad = 0.f, ap = 0.f;
    for (int k = 0; k < 64; k++) {
        float s = rdlane(v, k);
        ad = fmaf(s, Wd_top[k * 64 + lane], ad);
        ap = fmaf(s, Wp_top[k * 64 + lane], ap);
    }
    op_d[wid * 64 + lane] = ad;
    op_p[wid * 64 + lane] = ap;
}

// ---------------- nf projections via MFMA ----------------
__global__ __launch_bounds__(256) void nf_mfma_k(const float* __restrict__ nf,
                                                 const u16* __restrict__ WdT0,
                                                 const u16* __restrict__ WpT0,
                                                 u16* __restrict__ nf_d,
                                                 u16* __restrict__ nf_p) {
    int lane = threadIdx.x & 63;
    int m = lane & 15, q = lane >> 4;
    int wid = (blockIdx.x * 256 + threadIdx.x) >> 6;
    int nw = (gridDim.x * 256) >> 6;
    for (int rb = wid; rb < NN / 16; rb += nw) {
        int node0 = rb * 16;
        const float* row = nf + (size_t)(node0 + m) * 140;
        short8 af[5];
#pragma unroll
        for (int s = 0; s < 5; s++) {
            int k0 = s * 32 + q * 8;
            float f[8];
            if (s < 4) {
                fv4 lo = __builtin_nontemporal_load((const fv4*)(row + k0));
                fv4 hi = __builtin_nontemporal_load((const fv4*)(row + k0 + 4));
                f[0]=lo.x; f[1]=lo.y; f[2]=lo.z; f[3]=lo.w;
                f[4]=hi.x; f[5]=hi.y; f[6]=hi.z; f[7]=hi.w;
            } else {
#pragma unroll
                for (int j = 0; j < 8; j++) f[j] = 0.f;
                if (q == 0) {
                    fv4 lo = __builtin_nontemporal_load((const fv4*)(row + 128));
                    fv4 hi = __builtin_nontemporal_load((const fv4*)(row + 132));
                    f[0]=lo.x; f[1]=lo.y; f[2]=lo.z; f[3]=lo.w;
                    f[4]=hi.x; f[5]=hi.y; f[6]=hi.z; f[7]=hi.w;
                } else if (q == 1) {
                    fv4 lo = __builtin_nontemporal_load((const fv4*)(row + 136));
                    f[0]=lo.x; f[1]=lo.y; f[2]=lo.z; f[3]=lo.w;
                }
            }
            short8 t;
#pragma unroll
            for (int j = 0; j < 8; j++) t[j] = (short)f2b(f[j]);
            af[s] = t;
        }
        f32x4 ad[4], ap[4];
#pragma unroll
        for (int t = 0; t < 4; t++) {
            ad[t] = (f32x4){0.f, 0.f, 0.f, 0.f};
            ap[t] = (f32x4){0.f, 0.f, 0.f, 0.f};
        }
#pragma unroll
        for (int s = 0; s < 5; s++) {
#pragma unroll
            for (int t = 0; t < 4; t++) {
                int boff = (t * 16 + m) * 160 + s * 32 + q * 8;
                short8 bdw = ld_frag(WdT0 + boff);
                short8 bpw = ld_frag(WpT0 + boff);
                ad[t] = __builtin_amdgcn_mfma_f32_16x16x32_bf16(af[s], bdw, ad[t], 0, 0, 0);
                ap[t] = __builtin_amdgcn_mfma_f32_16x16x32_bf16(af[s], bpw, ap[t], 0, 0, 0);
            }
        }
#pragma unroll
        for (int r = 0; r < 4; r++) {
            size_t nrow = (size_t)(node0 + q * 4 + r);
#pragma unroll
            for (int t = 0; t < 4; t++) {
                nf_d[nrow * 64 + t * 16 + m] = (u16)f2b(ad[t][r]);
                nf_p[nrow * 64 + t * 16 + m] = (u16)f2b(ap[t][r]);
            }
        }
    }
}

// X[row=(n,c)][l] (bf16) = op_d[op[n]][l] + nf_d[n][l] + cf[n,c,:] @ Wbot
__global__ __launch_bounds__(256) void hd0_asm_k(u16* __restrict__ X,
                                                 const float* __restrict__ cf,
                                                 const int* __restrict__ op_ids,
                                                 const u16* __restrict__ nf_d,
                                                 const float* __restrict__ op_d,
                                                 const float* __restrict__ Wbot) {
    int lane = threadIdx.x & 63;
    float wb[18];
#pragma unroll
    for (int k = 0; k < 18; k++) wb[k] = Wbot[k * 64 + lane];
    int wid = (blockIdx.x * 256 + threadIdx.x) >> 6;
    int nw = (gridDim.x * 256) >> 6;
    for (int row = wid; row < NROWS; row += nw) {
        int n = row >> 3;
        float cfv = (lane < 18) ? __builtin_nontemporal_load(cf + (size_t)row * 18 + lane) : 0.f;
        float acc = op_d[op_ids[n] * 64 + lane] + b2f(nf_d[(size_t)n * 64 + lane]);
#pragma unroll
        for (int k = 0; k < 18; k++) acc = fmaf(rdlane(cfv, k), wb[k], acc);
        X[(size_t)row * 64 + lane] = (u16)f2b(acc);   // cached: gather target
    }
}

// ---------------- SpMM layer 0 (unfused), unroll-4, nt store (Y stream) ----------------
__global__ __launch_bounds__(256) void spmm_k(const uint4* __restrict__ X4,
                                              uint4* __restrict__ Y4,
                                              const int* __restrict__ row_ptr,
                                              const int* __restrict__ col) {
    int wid = (blockIdx.x * 256 + threadIdx.x) >> 6;
    int lane = threadIdx.x & 63;
    if (wid >= NN) return;
    int start = row_ptr[wid];
    int end = row_ptr[wid + 1];
    float a[8] = {0.f, 0.f, 0.f, 0.f, 0.f, 0.f, 0.f, 0.f};
    int j = start;
    for (; j + 4 <= end; j += 4) {
        int s0 = col[j], s1 = col[j + 1], s2 = col[j + 2], s3 = col[j + 3];
        uint4 t0 = X4[(size_t)s0 * 64 + lane];
        uint4 t1 = X4[(size_t)s1 * 64 + lane];
        uint4 t2 = X4[(size_t)s2 * 64 + lane];
        uint4 t3 = X4[(size_t)s3 * 64 + lane];
        acc8(a, t0); acc8(a, t1); acc8(a, t2); acc8(a, t3);
    }
    for (; j < end; j++) {
        uint4 t0 = X4[(size_t)col[j] * 64 + lane];
        acc8(a, t0);
    }
    u32x4 o;
    o.x = pack2(a[0], a[1]);
    o.y = pack2(a[2], a[3]);
    o.z = pack2(a[4], a[5]);
    o.w = pack2(a[6], a[7]);
    __builtin_nontemporal_store(o, (u32x4*)Y4 + (size_t)wid * 64 + lane);
}

// ---------------- combine layer 0 ----------------
__global__ __launch_bounds__(256) void combine0_k(u16* __restrict__ X,
                                                  const u16* __restrict__ Y,
                                                  const float* __restrict__ cf,
                                                  const int* __restrict__ op_ids,
                                                  const u16* __restrict__ nf_p,
                                                  const float* __restrict__ op_p,
                                                  const float* __restrict__ WpBot,
                                                  const float* __restrict__ bd,
                                                  const float* __restrict__ bp) {
    int lane = threadIdx.x & 63;
    float wb[18];
#pragma unroll
    for (int k = 0; k < 18; k++) wb[k] = WpBot[k * 64 + lane];
    float bdl = bd[lane], bpl = bp[lane];
    int wid = (blockIdx.x * 256 + threadIdx.x) >> 6;
    int nw = (gridDim.x * 256) >> 6;
    for (int row = wid; row < NROWS; row += nw) {
        int n = row >> 3;
        float yv = b2f(__builtin_nontemporal_load(Y + (size_t)row * 64 + lane));
        float cfv = (lane < 18) ? __builtin_nontemporal_load(cf + (size_t)row * 18 + lane) : 0.f;
        float accp = op_p[op_ids[n] * 64 + lane] + b2f(nf_p[(size_t)n * 64 + lane]);
#pragma unroll
        for (int k = 0; k < 18; k++) accp = fmaf(rdlane(cfv, k), wb[k], accp);
        float t = accp + bpl + lrelu(yv + bdl);
        float sq = wave_sum64(t * t);
        X[(size_t)row * 64 + lane] = (u16)f2b(t * rsqrtf(fmaxf(sq, 1e-12f)));  // cached
    }
}

// ---------------- FUSED SpMM + combine (layers 1/2) ----------------
__global__ __launch_bounds__(256) void fused_spmm_combine_k(const u16* __restrict__ Xin,
                                                            u16* __restrict__ Xout,
                                                            const int* __restrict__ row_ptr,
                                                            const int* __restrict__ col,
                                                            const u16* __restrict__ WdT,
                                                            const u16* __restrict__ WpT,
                                                            const float* __restrict__ bd,
                                                            const float* __restrict__ bp) {
    __shared__ u16 lds_t[4 * 16 * 72];
    int lane = threadIdx.x & 63;
    u16* L = lds_t + (threadIdx.x >> 6) * (16 * 72);
    int m = lane & 15, q = lane >> 4;
    const uint4* X4 = (const uint4*)Xin;
    short8 bdf[4][2], bpf[4][2];
#pragma unroll
    for (int t = 0; t < 4; t++)
#pragma unroll
        for (int s = 0; s < 2; s++) {
            int off = (t * 16 + m) * 64 + s * 32 + q * 8;
            bdf[t][s] = ld_frag(WdT + off);
            bpf[t][s] = ld_frag(WpT + off);
        }
    float bdv[4], bpv[4];
#pragma unroll
    for (int t = 0; t < 4; t++) { bdv[t] = bd[t * 16 + m]; bpv[t] = bp[t * 16 + m]; }

    int wid = (blockIdx.x * 256 + threadIdx.x) >> 6;
    int nw = (gridDim.x * 256) >> 6;
    for (int pb = wid; pb < NN / 2; pb += nw) {
#pragma unroll
        for (int p = 0; p < 2; p++) {
            int node = pb * 2 + p;
            int start = row_ptr[node], end = row_ptr[node + 1];
            float a[8] = {0.f, 0.f, 0.f, 0.f, 0.f, 0.f, 0.f, 0.f};
            int j = start;
            for (; j + 4 <= end; j += 4) {
                int s0 = col[j], s1 = col[j + 1], s2 = col[j + 2], s3 = col[j + 3];
                uint4 t0 = X4[(size_t)s0 * 64 + lane];
                uint4 t1 = X4[(size_t)s1 * 64 + lane];
                uint4 t2 = X4[(size_t)s2 * 64 + lane];
                uint4 t3 = X4[(size_t)s3 * 64 + lane];
                acc8(a, t0); acc8(a, t1); acc8(a, t2); acc8(a, t3);
            }
            for (; j < end; j++) {
                uint4 t0 = X4[(size_t)col[j] * 64 + lane];
                acc8(a, t0);
            }
            uint4 o;
            o.x = pack2(a[0], a[1]);
            o.y = pack2(a[2], a[3]);
            o.z = pack2(a[4], a[5]);
            o.w = pack2(a[6], a[7]);
            *(uint4*)(L + (size_t)(p * 8 + (lane >> 3)) * 72 + (lane & 7) * 8) = o;
        }
        short8 ay0 = ld_frag(L + m * 72 + q * 8);
        short8 ay1 = ld_frag(L + m * 72 + 32 + q * 8);
        const u16* xr = Xin + ((size_t)(pb * 16 + m)) * 64 + q * 8;
        short8 ax0 = ld_frag(xr), ax1 = ld_frag(xr + 32);
        f32x4 ad[4], ap[4];
#pragma unroll
        for (int t = 0; t < 4; t++) {
            ad[t] = (f32x4){0.f, 0.f, 0.f, 0.f};
            ap[t] = (f32x4){0.f, 0.f, 0.f, 0.f};
        }
#pragma unroll
        for (int t = 0; t < 4; t++) {
            ad[t] = __builtin_amdgcn_mfma_f32_16x16x32_bf16(ay0, bdf[t][0], ad[t], 0, 0, 0);
            ad[t] = __builtin_amdgcn_mfma_f32_16x16x32_bf16(ay1, bdf[t][1], ad[t], 0, 0, 0);
            ap[t] = __builtin_amdgcn_mfma_f32_16x16x32_bf16(ax0, bpf[t][0], ap[t], 0, 0, 0);
            ap[t] = __builtin_amdgcn_mfma_f32_16x16x32_bf16(ax1, bpf[t][1], ap[t], 0, 0, 0);
        }
        float v[4][4], sq[4];
#pragma unroll
        for (int r = 0; r < 4; r++) sq[r] = 0.f;
#pragma unroll
        for (int t = 0; t < 4; t++)
#pragma unroll
            for (int r = 0; r < 4; r++) {
                float val = ap[t][r] + bpv[t] + lrelu(ad[t][r] + bdv[t]);
                v[t][r] = val;
                sq[r] += val * val;
            }
#pragma unroll
        for (int r = 0; r < 4; r++) {
#pragma unroll
            for (int mm = 1; mm < 16; mm <<= 1) sq[r] += __shfl_xor(sq[r], mm, 64);
            float sc = rsqrtf(fmaxf(sq[r], 1e-12f));
            u16* orow = Xout + ((size_t)(pb * 16 + q * 4 + r)) * 64 + m;
#pragma unroll
            for (int t = 0; t < 4; t++) orow[t * 16] = (u16)f2b(v[t][r] * sc);  // cached
        }
    }
}

// ---------------- pooling v2: 2048-block hierarchical + atomics ----------------
// Block covers contiguous node chunk; thread = (feat, c-pair): f=tid&63,
// c0=tid>>6 handles configs c0 and c0+4. Coalesced 128B/wave loads. Flush per
// graph boundary via f32 atomicAdd into zero-init pooled[16*8*64].
__global__ __launch_bounds__(256) void pool2_k(const u16* __restrict__ X,
                                               const int* __restrict__ graph_ids,
                                               float* __restrict__ pooled) {
    int chunk = (NN + gridDim.x - 1) / gridDim.x;
    int n0 = blockIdx.x * chunk;
    int n1 = min(n0 + chunk, NN);
    if (n0 >= n1) return;
    int f = threadIdx.x & 63;
    int c0 = threadIdx.x >> 6;          // 0..3 -> configs c0, c0+4
    float a0 = 0.f, a1 = 0.f;
    int cur = graph_ids[n0];
    for (int n = n0; n < n1; n++) {
        int g = graph_ids[n];
        if (g != cur) {
            atomicAdd(&pooled[(size_t)(cur * 8 + c0) * 64 + f], a0);
            atomicAdd(&pooled[(size_t)(cur * 8 + c0 + 4) * 64 + f], a1);
            a0 = 0.f; a1 = 0.f; cur = g;
        }
        a0 += b2f(X[((size_t)n * 8 + c0) * 64 + f]);
        a1 += b2f(X[((size_t)n * 8 + c0 + 4) * 64 + f]);
    }
    atomicAdd(&pooled[(size_t)(cur * 8 + c0) * 64 + f], a0);
    atomicAdd(&pooled[(size_t)(cur * 8 + c0 + 4) * 64 + f], a1);
}

// ---------------- final MLP over 128 (b,c) rows ----------------
__global__ __launch_bounds__(256) void mlp_k(const float* __restrict__ pooled,
                                             const float* __restrict__ W0, const float* __restrict__ b0,
                                             const float* __restrict__ W1, const float* __restrict__ b1,
                                             const float* __restrict__ W2, const float* __restrict__ b2,
                                             float* __restrict__ out) {
    int lane = threadIdx.x & 63;
    int row = blockIdx.x * 4 + (threadIdx.x >> 6);
    if (row >= BB * CC) return;
    float b0l = b0[lane], b1l = b1[lane], w2l = W2[lane], b2s = b2[0];
    float p = pooled[(size_t)row * 64 + lane];
    float a = 0.f;
    for (int k = 0; k < 64; k++) a = fmaf(rdlane(p, k), W0[k * 64 + lane], a);
    float h0 = lrelu(a + b0l);
    float a1 = 0.f;
    for (int k = 0; k < 64; k++) a1 = fmaf(rdlane(h0, k), W1[k * 64 + lane], a1);
    float h1 = lrelu(a1 + b1l);
    float v = wave_sum64(h1 * w2l);
    if (lane == 0) out[row] = v + b2s;
}

extern "C" void kernel_launch(void* const* d_in, const int* in_sizes, int n_in,
                              void* d_out, int out_size, void* d_ws, size_t ws_size,
                              hipStream_t stream) {
    const float* node_feats   = (const float*)d_in[0];
    const float* config_feats = (const float*)d_in[1];
    const int*   op_ids       = (const int*)d_in[2];
    const int*   src          = (const int*)d_in[3];
    const int*   dst          = (const int*)d_in[4];
    const int*   graph_ids    = (const int*)d_in[5];
    const float* op_emb       = (const float*)d_in[6];
    const float* W_d0 = (const float*)d_in[7],  *b_d0 = (const float*)d_in[8];
    const float* W_p0 = (const float*)d_in[9],  *b_p0 = (const float*)d_in[10];
    const float* W_d1 = (const float*)d_in[11], *b_d1 = (const float*)d_in[12];
    const float* W_p1 = (const float*)d_in[13], *b_p1 = (const float*)d_in[14];
    const float* W_d2 = (const float*)d_in[15], *b_d2 = (const float*)d_in[16];
    const float* W_p2 = (const float*)d_in[17], *b_p2 = (const float*)d_in[18];
    const float* W_m0 = (const float*)d_in[19], *b_m0 = (const float*)d_in[20];
    const float* W_m1 = (const float*)d_in[21], *b_m1 = (const float*)d_in[22];
    const float* W_m2 = (const float*)d_in[23], *b_m2 = (const float*)d_in[24];
    float* out = (float*)d_out;

    // workspace layout (~233 MiB). X/XB ping-pong; XB doubles as layer-0 Y.
    char* ws = (char*)d_ws;
    size_t off = 0;
    u16* X       = (u16*)(ws + off); off += (size_t)NROWS * 64 * 2;   // 102.4 MB
    u16* XB      = (u16*)(ws + off); off += (size_t)NROWS * 64 * 2;   // 102.4 MB
    u16* nf_d    = (u16*)(ws + off); off += (size_t)NN * 64 * 2;      // 12.8 MB
    u16* nf_p    = (u16*)(ws + off); off += (size_t)NN * 64 * 2;      // 12.8 MB
    float* op_d  = (float*)(ws + off); off += 120 * 64 * 4;
    float* op_p  = (float*)(ws + off); off += 120 * 64 * 4;
    int* row_ptr = (int*)(ws + off);   off += 400128;                 // N+1 padded
    int* cursor  = (int*)(ws + off);   off += 400128;
    int* deg     = (int*)(ws + off);   off += 400128;
    int* bsum    = (int*)(ws + off);   off += 512;                    // 98+1 padded
    int* col     = (int*)(ws + off);   off += (size_t)2 * EE * 4;     // 12.8 MB
    float* pooled = (float*)(ws + off); off += BB * CC * 64 * 4;
    u16* WT      = (u16*)(ws + off);   off += (4 * 4096 + 2 * 10240) * 2;
    (void)ws_size; (void)in_sizes; (void)n_in; (void)out_size;

    const int NB = (NN + 1023) / 1024;   // 98 scan blocks

    // ---- CSR build + weight prep ----
    hipMemsetAsync(deg, 0, (size_t)NN * 4, stream);
    hipMemsetAsync(pooled, 0, (size_t)BB * CC * 64 * 4, stream);
    deg_count_k<<<(2 * EE) / 256, 256, 0, stream>>>(src, dst, deg);
    prep_w_k<<<144, 256, 0, stream>>>(W_d1, W_p1, W_d2, W_p2,
                                      W_d0 + 64 * 64, W_p0 + 64 * 64, WT);
    scan1_k<<<NB, 1024, 0, stream>>>(deg, row_ptr, bsum, NN);
    scan2_k<<<1, 1, 0, stream>>>(bsum, NB);
    scan3_k<<<NB, 1024, 0, stream>>>(row_ptr, cursor, bsum, NN, NB);
    place_k<<<(2 * EE) / 256, 256, 0, stream>>>(src, dst, cursor, col);

    // ---- input projections ----
    op_dp_k<<<30, 256, 0, stream>>>(op_emb, W_d0, W_p0, op_d, op_p);
    nf_mfma_k<<<512, 256, 0, stream>>>(node_feats, WT + 16384, WT + 16384 + 10240, nf_d, nf_p);
    hd0_asm_k<<<2048, 256, 0, stream>>>(X, config_feats, op_ids, nf_d, op_d, W_d0 + 204 * 64);

    // ---- layer 0 (unfused: elementwise combine, no matmul needed) ----
    spmm_k<<<NN / 4, 256, 0, stream>>>((const uint4*)X, (uint4*)XB, row_ptr, col);
    combine0_k<<<2048, 256, 0, stream>>>(X, XB, config_feats, op_ids, nf_p, op_p,
                                         W_p0 + 204 * 64, b_d0, b_p0);
    // ---- layers 1,2: fused SpMM+combine, ping-pong X <-> XB ----
    fused_spmm_combine_k<<<4096, 256, 0, stream>>>(X, XB, row_ptr, col,
                                                   WT, WT + 4096, b_d1, b_p1);
    fused_spmm_combine_k<<<4096, 256, 0, stream>>>(XB, X, row_ptr, col,
                                                   WT + 8192, WT + 12288, b_d2, b_p2);

    // ---- pooling + MLP ----
    pool2_k<<<2048, 256, 0, stream>>>(X, graph_ids, pooled);
    mlp_k<<<32, 256, 0, stream>>>(pooled, W_m0, b_m0, W_m1, b_m1, W_m2, b_m2, out);
}

// Round 8
// 2150.322 us; speedup vs baseline: 1.3390x; 1.0634x over previous
//
#include <hip/hip_runtime.h>
#include <hip/hip_bf16.h>

// Problem constants (match reference)
#define NN 100000
#define EE 1600000
#define CC 8
#define HH 64
#define NF 140
#define CF 18
#define BB 16
#define NROWS (NN * CC)          // 800000 rows of [64]
#define ALPHA 0.2f

// X layout: interleaved [n][c][64] (row = n*8+c).
// R8: layer 0 fully fused. hd0 emits X = x0@Wd0 and XP = x0@Wp0; fused_l0
// gathers X and applies the elementwise combine IN-PLACE over XP (safe: each
// 16B segment is read+written by exactly one lane). combine0 + Y round-trip
// deleted. Buffer flow: hd0->X,XP ; l0: gather X, XP->XP ; l1: XP->X ;
// l2: X->XP ; pool reads XP.

typedef unsigned short u16;
typedef unsigned int u32;
typedef __attribute__((ext_vector_type(8))) short short8;   // 8 bf16 (4 VGPRs)
typedef __attribute__((ext_vector_type(4))) float f32x4;    // MFMA accum
typedef __attribute__((ext_vector_type(4))) float fv4;

__device__ __forceinline__ float rdlane(float v, int l) {
    return __int_as_float(__builtin_amdgcn_readlane(__float_as_int(v), l));
}
__device__ __forceinline__ float lrelu(float x) { return x > 0.f ? x : ALPHA * x; }
__device__ __forceinline__ float wave_sum64(float v) {
#pragma unroll
    for (int m = 1; m < 64; m <<= 1) v += __shfl_xor(v, m, 64);
    return v;
}
__device__ __forceinline__ float b2f(u16 u) { return __uint_as_float(((u32)u) << 16); }
__device__ __forceinline__ u32 f2b(float f) {
    u32 u = __float_as_uint(f);
    return (u + 0x7fffu + ((u >> 16) & 1u)) >> 16;
}
__device__ __forceinline__ u32 pack2(float lo, float hi) {
    return f2b(lo) | (f2b(hi) << 16);
}
__device__ __forceinline__ short8 ld_frag(const u16* p) {
    union { uint4 u; short8 s; } c;
    c.u = *(const uint4*)p;
    return c.s;
}
__device__ __forceinline__ void acc8(float* a, uint4 t) {
    a[0] += __uint_as_float(t.x << 16); a[1] += __uint_as_float(t.x & 0xffff0000u);
    a[2] += __uint_as_float(t.y << 16); a[3] += __uint_as_float(t.y & 0xffff0000u);
    a[4] += __uint_as_float(t.z << 16); a[5] += __uint_as_float(t.z & 0xffff0000u);
    a[6] += __uint_as_float(t.w << 16); a[7] += __uint_as_float(t.w & 0xffff0000u);
}

// ---------------- CSR build ----------------
__global__ __launch_bounds__(256) void deg_count_k(const int* __restrict__ src,
                                                   const int* __restrict__ dst,
                                                   int* __restrict__ deg) {
    int e = blockIdx.x * 256 + threadIdx.x;
    if (e < EE) atomicAdd(&deg[dst[e]], 1);
    else if (e < 2 * EE) atomicAdd(&deg[src[e - EE]], 1);
}

__global__ __launch_bounds__(1024) void scan1_k(const int* __restrict__ deg,
                                                int* __restrict__ row_ptr,
                                                int* __restrict__ bsum, int n) {
    __shared__ int lds[17];
    int i = blockIdx.x * 1024 + threadIdx.x;
    int lane = threadIdx.x & 63, wv = threadIdx.x >> 6;
    int val = (i < n) ? deg[i] : 0;
    int v = val;
#pragma unroll
    for (int d = 1; d < 64; d <<= 1) {
        int t = __shfl_up(v, d, 64);
        if (lane >= d) v += t;
    }
    if (lane == 63) lds[wv] = v;
    __syncthreads();
    if (threadIdx.x == 0) {
        int run = 0;
#pragma unroll
        for (int k = 0; k < 16; k++) { int t = lds[k]; lds[k] = run; run += t; }
        lds[16] = run;
    }
    __syncthreads();
    if (i < n) row_ptr[i] = v - val + lds[wv];
    if (threadIdx.x == 1023) bsum[blockIdx.x] = lds[16];
}

__global__ void scan2_k(int* __restrict__ bsum, int nb) {
    int run = 0;
    for (int b = 0; b < nb; b++) { int t = bsum[b]; bsum[b] = run; run += t; }
    bsum[nb] = run;
}

__global__ __launch_bounds__(1024) void scan3_k(int* __restrict__ row_ptr,
                                                int* __restrict__ cursor,
                                                const int* __restrict__ bsum,
                                                int n, int nb) {
    int i = blockIdx.x * 1024 + threadIdx.x;
    if (i < n) {
        int v = row_ptr[i] + bsum[blockIdx.x];
        row_ptr[i] = v;
        cursor[i] = v;
    }
    if (i == 0) row_ptr[n] = bsum[nb];
}

__global__ __launch_bounds__(256) void place_k(const int* __restrict__ src,
                                               const int* __restrict__ dst,
                                               int* __restrict__ cursor,
                                               int* __restrict__ col) {
    int e = blockIdx.x * 256 + threadIdx.x;
    int node, other;
    if (e < EE) { node = dst[e]; other = src[e]; }
    else if (e < 2 * EE) { node = src[e - EE]; other = dst[e - EE]; }
    else return;
    int pos = atomicAdd(&cursor[node], 1);
    col[pos] = other;
}

// ---------------- weight prep: transposed bf16 weights ----------------
__global__ __launch_bounds__(256) void prep_w_k(const float* __restrict__ Wd1, const float* __restrict__ Wp1,
                                                const float* __restrict__ Wd2, const float* __restrict__ Wp2,
                                                const float* __restrict__ Wd0nf, const float* __restrict__ Wp0nf,
                                                u16* __restrict__ WT) {
    int i = blockIdx.x * 256 + threadIdx.x;
    if (i < 4 * 4096) {
        int w = i >> 12, idx = i & 4095;
        int n = idx >> 6, k = idx & 63;
        const float* W = (w == 0) ? Wd1 : (w == 1) ? Wp1 : (w == 2) ? Wd2 : Wp2;
        WT[w * 4096 + n * 64 + k] = (u16)f2b(W[k * 64 + n]);
    } else {
        int j = i - 4 * 4096;
        if (j < 2 * 64 * 160) {
            int w = j / 10240, idx = j % 10240;
            int n = idx / 160, k = idx % 160;
            const float* W = w ? Wp0nf : Wd0nf;
            WT[16384 + w * 10240 + n * 160 + k] = (k < 140) ? (u16)f2b(W[k * 64 + n]) : (u16)0;
        }
    }
}

// op_d/op_p tables: [120][64] f32 = op_emb @ W_top (rows 0..63 of W_d0 / W_p0)
__global__ __launch_bounds__(256) void op_dp_k(const float* __restrict__ op_emb,
                                               const float* __restrict__ Wd_top,
                                               const float* __restrict__ Wp_top,
                                               float* __restrict__ op_d,
                                               float* __restrict__ op_p) {
    int lane = threadIdx.x & 63;
    int wid = (blockIdx.x * 256 + threadIdx.x) >> 6;
    if (wid >= 120) return;
    float v = op_emb[wid * 64 + lane];
    float ad = 0.f, ap = 0.f;
    for (int k = 0; k < 64; k++) {
        float s = rdlane(v, k);
        ad = fmaf(s, Wd_top[k * 64 + lane], ad);
        ap = fmaf(s, Wp_top[k * 64 + lane], ap);
    }
    op_d[wid * 64 + lane] = ad;
    op_p[wid * 64 + lane] = ap;
}

// ---------------- nf projections via MFMA ----------------
__global__ __launch_bounds__(256) void nf_mfma_k(const float* __restrict__ nf,
                                                 const u16* __restrict__ WdT0,
                                                 const u16* __restrict__ WpT0,
                                                 u16* __restrict__ nf_d,
                                                 u16* __restrict__ nf_p) {
    int lane = threadIdx.x & 63;
    int m = lane & 15, q = lane >> 4;
    int wid = (blockIdx.x * 256 + threadIdx.x) >> 6;
    int nw = (gridDim.x * 256) >> 6;
    for (int rb = wid; rb < NN / 16; rb += nw) {
        int node0 = rb * 16;
        const float* row = nf + (size_t)(node0 + m) * 140;
        short8 af[5];
#pragma unroll
        for (int s = 0; s < 5; s++) {
            int k0 = s * 32 + q * 8;
            float f[8];
            if (s < 4) {
                fv4 lo = __builtin_nontemporal_load((const fv4*)(row + k0));
                fv4 hi = __builtin_nontemporal_load((const fv4*)(row + k0 + 4));
                f[0]=lo.x; f[1]=lo.y; f[2]=lo.z; f[3]=lo.w;
                f[4]=hi.x; f[5]=hi.y; f[6]=hi.z; f[7]=hi.w;
            } else {
#pragma unroll
                for (int j = 0; j < 8; j++) f[j] = 0.f;
                if (q == 0) {
                    fv4 lo = __builtin_nontemporal_load((const fv4*)(row + 128));
                    fv4 hi = __builtin_nontemporal_load((const fv4*)(row + 132));
                    f[0]=lo.x; f[1]=lo.y; f[2]=lo.z; f[3]=lo.w;
                    f[4]=hi.x; f[5]=hi.y; f[6]=hi.z; f[7]=hi.w;
                } else if (q == 1) {
                    fv4 lo = __builtin_nontemporal_load((const fv4*)(row + 136));
                    f[0]=lo.x; f[1]=lo.y; f[2]=lo.z; f[3]=lo.w;
                }
            }
            short8 t;
#pragma unroll
            for (int j = 0; j < 8; j++) t[j] = (short)f2b(f[j]);
            af[s] = t;
        }
        f32x4 ad[4], ap[4];
#pragma unroll
        for (int t = 0; t < 4; t++) {
            ad[t] = (f32x4){0.f, 0.f, 0.f, 0.f};
            ap[t] = (f32x4){0.f, 0.f, 0.f, 0.f};
        }
#pragma unroll
        for (int s = 0; s < 5; s++) {
#pragma unroll
            for (int t = 0; t < 4; t++) {
                int boff = (t * 16 + m) * 160 + s * 32 + q * 8;
                short8 bdw = ld_frag(WdT0 + boff);
                short8 bpw = ld_frag(WpT0 + boff);
                ad[t] = __builtin_amdgcn_mfma_f32_16x16x32_bf16(af[s], bdw, ad[t], 0, 0, 0);
                ap[t] = __builtin_amdgcn_mfma_f32_16x16x32_bf16(af[s], bpw, ap[t], 0, 0, 0);
            }
        }
#pragma unroll
        for (int r = 0; r < 4; r++) {
            size_t nrow = (size_t)(node0 + q * 4 + r);
#pragma unroll
            for (int t = 0; t < 4; t++) {
                nf_d[nrow * 64 + t * 16 + m] = (u16)f2b(ad[t][r]);
                nf_p[nrow * 64 + t * 16 + m] = (u16)f2b(ap[t][r]);
            }
        }
    }
}

// hd0 v2: X[row] = op_d + nf_d + cf@WdBot ; XP[row] = op_p + nf_p + cf@WpBot
__global__ __launch_bounds__(256) void hd0_dual_k(u16* __restrict__ X,
                                                  u16* __restrict__ XP,
                                                  const float* __restrict__ cf,
                                                  const int* __restrict__ op_ids,
                                                  const u16* __restrict__ nf_d,
                                                  const u16* __restrict__ nf_p,
                                                  const float* __restrict__ op_d,
                                                  const float* __restrict__ op_p,
                                                  const float* __restrict__ WdBot,
                                                  const float* __restrict__ WpBot) {
    int lane = threadIdx.x & 63;
    float wbd[18], wbp[18];
#pragma unroll
    for (int k = 0; k < 18; k++) { wbd[k] = WdBot[k * 64 + lane]; wbp[k] = WpBot[k * 64 + lane]; }
    int wid = (blockIdx.x * 256 + threadIdx.x) >> 6;
    int nw = (gridDim.x * 256) >> 6;
    for (int row = wid; row < NROWS; row += nw) {
        int n = row >> 3;
        float cfv = (lane < 18) ? __builtin_nontemporal_load(cf + (size_t)row * 18 + lane) : 0.f;
        int op = op_ids[n];
        float accd = op_d[op * 64 + lane] + b2f(nf_d[(size_t)n * 64 + lane]);
        float accp = op_p[op * 64 + lane] + b2f(nf_p[(size_t)n * 64 + lane]);
#pragma unroll
        for (int k = 0; k < 18; k++) {
            float s = rdlane(cfv, k);
            accd = fmaf(s, wbd[k], accd);
            accp = fmaf(s, wbp[k], accp);
        }
        X[(size_t)row * 64 + lane] = (u16)f2b(accd);
        XP[(size_t)row * 64 + lane] = (u16)f2b(accp);
    }
}

// ---------------- FUSED layer 0: gather X, elementwise combine in-place on XP ----------------
// One wave per node. lane covers row r=lane>>3 (config), feats fb=(lane&7)*8..+7.
// XPnew[row][fb..] = l2norm_row( XP + bp + lrelu(gather + bd) ). In-place safe:
// each 16B segment read+written by exactly its own lane; gather reads X only.
__global__ __launch_bounds__(256) void fused_l0_k(const uint4* __restrict__ X4,
                                                  u16* __restrict__ XP,
                                                  const int* __restrict__ row_ptr,
                                                  const int* __restrict__ col,
                                                  const float* __restrict__ bd,
                                                  const float* __restrict__ bp) {
    int wid = (blockIdx.x * 256 + threadIdx.x) >> 6;
    int lane = threadIdx.x & 63;
    if (wid >= NN) return;
    int r = lane >> 3, fb = (lane & 7) * 8;
    float bdv[8], bpv[8];
#pragma unroll
    for (int j = 0; j < 8; j++) { bdv[j] = bd[fb + j]; bpv[j] = bp[fb + j]; }
    int start = row_ptr[wid];
    int end = row_ptr[wid + 1];
    float a[8] = {0.f, 0.f, 0.f, 0.f, 0.f, 0.f, 0.f, 0.f};
    int j = start;
    for (; j + 8 <= end; j += 8) {
        uint4 t0 = X4[(size_t)col[j] * 64 + lane];
        uint4 t1 = X4[(size_t)col[j + 1] * 64 + lane];
        uint4 t2 = X4[(size_t)col[j + 2] * 64 + lane];
        uint4 t3 = X4[(size_t)col[j + 3] * 64 + lane];
        uint4 t4 = X4[(size_t)col[j + 4] * 64 + lane];
        uint4 t5 = X4[(size_t)col[j + 5] * 64 + lane];
        uint4 t6 = X4[(size_t)col[j + 6] * 64 + lane];
        uint4 t7 = X4[(size_t)col[j + 7] * 64 + lane];
        acc8(a, t0); acc8(a, t1); acc8(a, t2); acc8(a, t3);
        acc8(a, t4); acc8(a, t5); acc8(a, t6); acc8(a, t7);
    }
    for (; j < end; j++) {
        uint4 t0 = X4[(size_t)col[j] * 64 + lane];
        acc8(a, t0);
    }
    // epilogue
    size_t rowg = (size_t)wid * 8 + r;
    short8 xp = ld_frag(XP + rowg * 64 + fb);
    float v[8], sq = 0.f;
#pragma unroll
    for (int q = 0; q < 8; q++) {
        float val = b2f((u16)xp[q]) + bpv[q] + lrelu(a[q] + bdv[q]);
        v[q] = val;
        sq += val * val;
    }
    sq += __shfl_xor(sq, 1, 64);
    sq += __shfl_xor(sq, 2, 64);
    sq += __shfl_xor(sq, 4, 64);
    float sc = rsqrtf(fmaxf(sq, 1e-12f));
    uint4 o;
    o.x = pack2(v[0] * sc, v[1] * sc);
    o.y = pack2(v[2] * sc, v[3] * sc);
    o.z = pack2(v[4] * sc, v[5] * sc);
    o.w = pack2(v[6] * sc, v[7] * sc);
    *(uint4*)(XP + rowg * 64 + fb) = o;
}

// ---------------- FUSED SpMM + combine (layers 1/2) ----------------
__global__ __launch_bounds__(256) void fused_spmm_combine_k(const u16* __restrict__ Xin,
                                                            u16* __restrict__ Xout,
                                                            const int* __restrict__ row_ptr,
                                                            const int* __restrict__ col,
                                                            const u16* __restrict__ WdT,
                                                            const u16* __restrict__ WpT,
                                                            const float* __restrict__ bd,
                                                            const float* __restrict__ bp) {
    __shared__ u16 lds_t[4 * 16 * 72];
    int lane = threadIdx.x & 63;
    u16* L = lds_t + (threadIdx.x >> 6) * (16 * 72);
    int m = lane & 15, q = lane >> 4;
    const uint4* X4 = (const uint4*)Xin;
    short8 bdf[4][2], bpf[4][2];
#pragma unroll
    for (int t = 0; t < 4; t++)
#pragma unroll
        for (int s = 0; s < 2; s++) {
            int off = (t * 16 + m) * 64 + s * 32 + q * 8;
            bdf[t][s] = ld_frag(WdT + off);
            bpf[t][s] = ld_frag(WpT + off);
        }
    float bdv[4], bpv[4];
#pragma unroll
    for (int t = 0; t < 4; t++) { bdv[t] = bd[t * 16 + m]; bpv[t] = bp[t * 16 + m]; }

    int wid = (blockIdx.x * 256 + threadIdx.x) >> 6;
    int nw = (gridDim.x * 256) >> 6;
    for (int pb = wid; pb < NN / 2; pb += nw) {
#pragma unroll
        for (int p = 0; p < 2; p++) {
            int node = pb * 2 + p;
            int start = row_ptr[node], end = row_ptr[node + 1];
            float a[8] = {0.f, 0.f, 0.f, 0.f, 0.f, 0.f, 0.f, 0.f};
            int j = start;
            for (; j + 4 <= end; j += 4) {
                int s0 = col[j], s1 = col[j + 1], s2 = col[j + 2], s3 = col[j + 3];
                uint4 t0 = X4[(size_t)s0 * 64 + lane];
                uint4 t1 = X4[(size_t)s1 * 64 + lane];
                uint4 t2 = X4[(size_t)s2 * 64 + lane];
                uint4 t3 = X4[(size_t)s3 * 64 + lane];
                acc8(a, t0); acc8(a, t1); acc8(a, t2); acc8(a, t3);
            }
            for (; j < end; j++) {
                uint4 t0 = X4[(size_t)col[j] * 64 + lane];
                acc8(a, t0);
            }
            uint4 o;
            o.x = pack2(a[0], a[1]);
            o.y = pack2(a[2], a[3]);
            o.z = pack2(a[4], a[5]);
            o.w = pack2(a[6], a[7]);
            *(uint4*)(L + (size_t)(p * 8 + (lane >> 3)) * 72 + (lane & 7) * 8) = o;
        }
        short8 ay0 = ld_frag(L + m * 72 + q * 8);
        short8 ay1 = ld_frag(L + m * 72 + 32 + q * 8);
        const u16* xr = Xin + ((size_t)(pb * 16 + m)) * 64 + q * 8;
        short8 ax0 = ld_frag(xr), ax1 = ld_frag(xr + 32);
        f32x4 ad[4], ap[4];
#pragma unroll
        for (int t = 0; t < 4; t++) {
            ad[t] = (f32x4){0.f, 0.f, 0.f, 0.f};
            ap[t] = (f32x4){0.f, 0.f, 0.f, 0.f};
        }
#pragma unroll
        for (int t = 0; t < 4; t++) {
            ad[t] = __builtin_amdgcn_mfma_f32_16x16x32_bf16(ay0, bdf[t][0], ad[t], 0, 0, 0);
            ad[t] = __builtin_amdgcn_mfma_f32_16x16x32_bf16(ay1, bdf[t][1], ad[t], 0, 0, 0);
            ap[t] = __builtin_amdgcn_mfma_f32_16x16x32_bf16(ax0, bpf[t][0], ap[t], 0, 0, 0);
            ap[t] = __builtin_amdgcn_mfma_f32_16x16x32_bf16(ax1, bpf[t][1], ap[t], 0, 0, 0);
        }
        float v[4][4], sq[4];
#pragma unroll
        for (int r = 0; r < 4; r++) sq[r] = 0.f;
#pragma unroll
        for (int t = 0; t < 4; t++)
#pragma unroll
            for (int r = 0; r < 4; r++) {
                float val = ap[t][r] + bpv[t] + lrelu(ad[t][r] + bdv[t]);
                v[t][r] = val;
                sq[r] += val * val;
            }
#pragma unroll
        for (int r = 0; r < 4; r++) {
#pragma unroll
            for (int mm = 1; mm < 16; mm <<= 1) sq[r] += __shfl_xor(sq[r], mm, 64);
            float sc = rsqrtf(fmaxf(sq[r], 1e-12f));
            u16* orow = Xout + ((size_t)(pb * 16 + q * 4 + r)) * 64 + m;
#pragma unroll
            for (int t = 0; t < 4; t++) orow[t * 16] = (u16)f2b(v[t][r] * sc);
        }
    }
}

// ---------------- pooling: hierarchical + atomics ----------------
__global__ __launch_bounds__(256) void pool2_k(const u16* __restrict__ X,
                                               const int* __restrict__ graph_ids,
                                               float* __restrict__ pooled) {
    int chunk = (NN + gridDim.x - 1) / gridDim.x;
    int n0 = blockIdx.x * chunk;
    int n1 = min(n0 + chunk, NN);
    if (n0 >= n1) return;
    int f = threadIdx.x & 63;
    int c0 = threadIdx.x >> 6;          // 0..3 -> configs c0, c0+4
    float a0 = 0.f, a1 = 0.f;
    int cur = graph_ids[n0];
    for (int n = n0; n < n1; n++) {
        int g = graph_ids[n];
        if (g != cur) {
            atomicAdd(&pooled[(size_t)(cur * 8 + c0) * 64 + f], a0);
            atomicAdd(&pooled[(size_t)(cur * 8 + c0 + 4) * 64 + f], a1);
            a0 = 0.f; a1 = 0.f; cur = g;
        }
        a0 += b2f(X[((size_t)n * 8 + c0) * 64 + f]);
        a1 += b2f(X[((size_t)n * 8 + c0 + 4) * 64 + f]);
    }
    atomicAdd(&pooled[(size_t)(cur * 8 + c0) * 64 + f], a0);
    atomicAdd(&pooled[(size_t)(cur * 8 + c0 + 4) * 64 + f], a1);
}

// ---------------- final MLP over 128 (b,c) rows ----------------
__global__ __launch_bounds__(256) void mlp_k(const float* __restrict__ pooled,
                                             const float* __restrict__ W0, const float* __restrict__ b0,
                                             const float* __restrict__ W1, const float* __restrict__ b1,
                                             const float* __restrict__ W2, const float* __restrict__ b2,
                                             float* __restrict__ out) {
    int lane = threadIdx.x & 63;
    int row = blockIdx.x * 4 + (threadIdx.x >> 6);
    if (row >= BB * CC) return;
    float b0l = b0[lane], b1l = b1[lane], w2l = W2[lane], b2s = b2[0];
    float p = pooled[(size_t)row * 64 + lane];
    float a = 0.f;
    for (int k = 0; k < 64; k++) a = fmaf(rdlane(p, k), W0[k * 64 + lane], a);
    float h0 = lrelu(a + b0l);
    float a1 = 0.f;
    for (int k = 0; k < 64; k++) a1 = fmaf(rdlane(h0, k), W1[k * 64 + lane], a1);
    float h1 = lrelu(a1 + b1l);
    float v = wave_sum64(h1 * w2l);
    if (lane == 0) out[row] = v + b2s;
}

extern "C" void kernel_launch(void* const* d_in, const int* in_sizes, int n_in,
                              void* d_out, int out_size, void* d_ws, size_t ws_size,
                              hipStream_t stream) {
    const float* node_feats   = (const float*)d_in[0];
    const float* config_feats = (const float*)d_in[1];
    const int*   op_ids       = (const int*)d_in[2];
    const int*   src          = (const int*)d_in[3];
    const int*   dst          = (const int*)d_in[4];
    const int*   graph_ids    = (const int*)d_in[5];
    const float* op_emb       = (const float*)d_in[6];
    const float* W_d0 = (const float*)d_in[7],  *b_d0 = (const float*)d_in[8];
    const float* W_p0 = (const float*)d_in[9],  *b_p0 = (const float*)d_in[10];
    const float* W_d1 = (const float*)d_in[11], *b_d1 = (const float*)d_in[12];
    const float* W_p1 = (const float*)d_in[13], *b_p1 = (const float*)d_in[14];
    const float* W_d2 = (const float*)d_in[15], *b_d2 = (const float*)d_in[16];
    const float* W_p2 = (const float*)d_in[17], *b_p2 = (const float*)d_in[18];
    const float* W_m0 = (const float*)d_in[19], *b_m0 = (const float*)d_in[20];
    const float* W_m1 = (const float*)d_in[21], *b_m1 = (const float*)d_in[22];
    const float* W_m2 = (const float*)d_in[23], *b_m2 = (const float*)d_in[24];
    float* out = (float*)d_out;

    // workspace layout (~233 MiB). X / XP ping-pong.
    char* ws = (char*)d_ws;
    size_t off = 0;
    u16* X       = (u16*)(ws + off); off += (size_t)NROWS * 64 * 2;   // 102.4 MB
    u16* XP      = (u16*)(ws + off); off += (size_t)NROWS * 64 * 2;   // 102.4 MB
    u16* nf_d    = (u16*)(ws + off); off += (size_t)NN * 64 * 2;      // 12.8 MB
    u16* nf_p    = (u16*)(ws + off); off += (size_t)NN * 64 * 2;      // 12.8 MB
    float* op_d  = (float*)(ws + off); off += 120 * 64 * 4;
    float* op_p  = (float*)(ws + off); off += 120 * 64 * 4;
    int* row_ptr = (int*)(ws + off);   off += 400128;                 // N+1 padded
    int* cursor  = (int*)(ws + off);   off += 400128;
    int* deg     = (int*)(ws + off);   off += 400128;
    int* bsum    = (int*)(ws + off);   off += 512;                    // 98+1 padded
    int* col     = (int*)(ws + off);   off += (size_t)2 * EE * 4;     // 12.8 MB
    float* pooled = (float*)(ws + off); off += BB * CC * 64 * 4;
    u16* WT      = (u16*)(ws + off);   off += (4 * 4096 + 2 * 10240) * 2;
    (void)ws_size; (void)in_sizes; (void)n_in; (void)out_size;

    const int NB = (NN + 1023) / 1024;   // 98 scan blocks

    // ---- CSR build + weight prep ----
    hipMemsetAsync(deg, 0, (size_t)NN * 4, stream);
    hipMemsetAsync(pooled, 0, (size_t)BB * CC * 64 * 4, stream);
    deg_count_k<<<(2 * EE) / 256, 256, 0, stream>>>(src, dst, deg);
    prep_w_k<<<144, 256, 0, stream>>>(W_d1, W_p1, W_d2, W_p2,
                                      W_d0 + 64 * 64, W_p0 + 64 * 64, WT);
    scan1_k<<<NB, 1024, 0, stream>>>(deg, row_ptr, bsum, NN);
    scan2_k<<<1, 1, 0, stream>>>(bsum, NB);
    scan3_k<<<NB, 1024, 0, stream>>>(row_ptr, cursor, bsum, NN, NB);
    place_k<<<(2 * EE) / 256, 256, 0, stream>>>(src, dst, cursor, col);

    // ---- input projections ----
    op_dp_k<<<30, 256, 0, stream>>>(op_emb, W_d0, W_p0, op_d, op_p);
    nf_mfma_k<<<512, 256, 0, stream>>>(node_feats, WT + 16384, WT + 16384 + 10240, nf_d, nf_p);
    hd0_dual_k<<<2048, 256, 0, stream>>>(X, XP, config_feats, op_ids, nf_d, nf_p,
                                         op_d, op_p, W_d0 + 204 * 64, W_p0 + 204 * 64);

    // ---- layer 0: fused gather + elementwise combine, in-place on XP ----
    fused_l0_k<<<NN / 4, 256, 0, stream>>>((const uint4*)X, XP, row_ptr, col, b_d0, b_p0);
    // ---- layers 1,2: fused SpMM+combine, ping-pong XP <-> X ----
    fused_spmm_combine_k<<<4096, 256, 0, stream>>>(XP, X, row_ptr, col,
                                                   WT, WT + 4096, b_d1, b_p1);
    fused_spmm_combine_k<<<4096, 256, 0, stream>>>(X, XP, row_ptr, col,
                                                   WT + 8192, WT + 12288, b_d2, b_p2);

    // ---- pooling + MLP ----
    pool2_k<<<2048, 256, 0, stream>>>(XP, graph_ids, pooled);
    mlp_k<<<32, 256, 0, stream>>>(pooled, W_m0, b_m0, W_m1, b_m1, W_m2, b_m2, out);
}